// Round 12
// baseline (470.655 us; speedup 1.0000x reference)
//
#include <hip/hip_runtime.h>
#include <hip/hip_bf16.h>
#include <math.h>

#define TOK   4096
#define DIM   1024
#define DMLP  4096
#define NE    8
#define BM    128
#define BN    128
#define BN2   64
#define BK    64
#define PADMAX (TOK + NE * BM)   // 5120 padded slots
#define NTILES (PADMAX / BM)     // 40 row-tiles
#define MAXSUP 24                // max 256-row supertiles

typedef __attribute__((ext_vector_type(8))) short  short8;
typedef __attribute__((ext_vector_type(4))) float  float4v;
typedef __attribute__((ext_vector_type(4))) unsigned short ushort4v;
typedef __attribute__((ext_vector_type(2))) unsigned long long ull2;

// async global->LDS, 16 B per lane; LDS dest is wave-uniform base + lane*16
#define ASYNC16(gp, lp) __builtin_amdgcn_global_load_lds( \
    (const __attribute__((address_space(1))) unsigned int*)(gp), \
    (__attribute__((address_space(3))) unsigned int*)(lp), 16, 0, 0)

// BK=64: 8 granules (8 bf16 = 16 B) per row. A-side swizzle (r0-proven).
#define FRAG_OFF(R, C) ((((R) << 3) + ((C) ^ ((R) & 7))) << 3)
// B-side LDS layout (granule-major): [C][n][8], n<128, offset in shorts
#define BOFF(C, n) ((((C) << 7) + (n)) << 3)

static __device__ __forceinline__ unsigned short f2bf(float f) {
  unsigned u = __float_as_uint(f);
  u += 0x7fffu + ((u >> 16) & 1u);
  return (unsigned short)(u >> 16);
}

// exact-erf GELU via Abramowitz&Stegun 7.1.26 (|err| < 1.5e-7)
static __device__ __forceinline__ float gelu_erf(float v) {
  const float x = fabsf(v) * 0.70710678118654752f;
  const float t = __builtin_amdgcn_rcpf(1.0f + 0.3275911f * x);
  const float poly = ((((1.061405429f * t - 1.453152027f) * t + 1.421413741f) * t
                       - 0.284496736f) * t + 0.254829592f) * t;
  const float erf_abs = 1.0f - poly * __expf(-x * x);
  return 0.5f * v * (1.0f + copysignf(erf_abs, v));
}

// ---------------------------------------------------------------------------
// Kernel 1: group tokens by expert (single block). 128-tile map + 256-row
// supertile descriptors (two same-expert 128-tiles; odd leftover self-pairs).
// ---------------------------------------------------------------------------
__global__ void group_kernel(const int* __restrict__ eidx,
                             int* __restrict__ perm,
                             int* __restrict__ tile_e,
                             int* __restrict__ supA,
                             int* __restrict__ supB,
                             int* __restrict__ supE) {
  __shared__ int cnt[NE], off[NE], len[NE], cur[NE];
  const int tid = threadIdx.x;
  if (tid < NE) cnt[tid] = 0;
  __syncthreads();
  for (int i = tid; i < TOK; i += 256) atomicAdd(&cnt[eidx[i]], 1);
  __syncthreads();
  if (tid == 0) {
    int o = 0;
    for (int e = 0; e < NE; e++) {
      off[e] = o;
      len[e] = ((cnt[e] + BM - 1) / BM) * BM;
      cur[e] = o;
      o += len[e];
    }
    int ns = 0;
    for (int e = 0; e < NE; e++) {
      const int nt = len[e] / BM;
      for (int p = 0; p < nt; p += 2) {
        const int pb = (p + 1 < nt) ? (p + 1) : p;
        supA[ns] = off[e] + p * BM;
        supB[ns] = off[e] + pb * BM;
        supE[ns] = e;
        ns++;
      }
    }
    for (; ns < MAXSUP; ns++) { supA[ns] = 0; supB[ns] = 0; supE[ns] = -1; }
  }
  __syncthreads();
  for (int s = tid; s < PADMAX; s += 256) perm[s] = -1;
  __syncthreads();
  for (int i = tid; i < TOK; i += 256) {
    const int e = eidx[i];
    const int p = atomicAdd(&cur[e], 1);
    perm[p] = i;
  }
  __syncthreads();
  for (int t = tid; t < NTILES; t += 256) {
    const int row = t * BM;
    int te = -1;
    for (int e = 0; e < NE; e++)
      if (row >= off[e] && row < off[e] + len[e]) te = e;
    tile_e[t] = te;
  }
}

// ---------------------------------------------------------------------------
// convpack body (r9 proven): W [K][N] f32 -> WT [K/8][N][8] bf16.
// ---------------------------------------------------------------------------
static __device__ __forceinline__
void convpack_body(const float* __restrict__ W, unsigned short* __restrict__ WT,
                   int K, int N, int kg, int nblk, int e, int tid) {
  const int n0 = nblk * 1024 + tid * 4;
  const float* Win = W + (size_t)e * K * N + (size_t)kg * 8 * N + n0;
  unsigned short* Wout = WT + (size_t)e * K * N + ((size_t)kg * N + n0) * 8;
  float4v v[8];
#pragma unroll
  for (int j = 0; j < 8; j++) v[j] = *(const float4v*)(Win + (size_t)j * N);
#pragma unroll
  for (int q = 0; q < 4; q++) {
    short8 g;
#pragma unroll
    for (int j = 0; j < 8; j++) g[j] = (short)f2bf(v[j][q]);
    *(short8*)(Wout + q * 8) = g;
  }
}

// ---------------------------------------------------------------------------
// Kernel 2 (prep1): convpack(W1) + xgather. (W2 conv is gemm1 tail work.)
// ---------------------------------------------------------------------------
__global__ __launch_bounds__(256)
void prep1_kernel(const float* __restrict__ W1, unsigned short* __restrict__ W1T,
                  const float* __restrict__ x, const int* __restrict__ perm,
                  unsigned short* __restrict__ xg) {
  const int bid = blockIdx.x;
  const int tid = threadIdx.x;
  if (bid < 4096) {
    convpack_body(W1, W1T, DIM, DMLP, bid & 127, (bid >> 7) & 3, bid >> 9, tid);
  } else {
    const int slot = bid - 4096;
    const int t    = perm[slot];
    ushort4v o = (ushort4v){0, 0, 0, 0};
    if (t >= 0) {
      const float4v v = *(const float4v*)(x + (size_t)t * DIM + tid * 4);
#pragma unroll
      for (int q = 0; q < 4; q++) o[q] = f2bf(v[q]);
    }
    *(ushort4v*)(xg + (size_t)slot * DIM + tid * 4) = o;
  }
}

// ---------------------------------------------------------------------------
// Kernel 3: h = gelu(xg @ W1 + b1) -> bf16. 128x128 tile, BK=64,
// DOUBLE-BUFFERED with COUNTED vmcnt (T3/T4): per step issue next tile's 8
// ASYNC16 into buf^1, s_waitcnt vmcnt(8) (waits only the PREVIOUS tile; the
// new 8 stay in flight through the MFMA phase), raw s_barrier, compute,
// raw s_barrier (WAR guard). No full drain in the main loop.
// 64 KB LDS -> 2 blocks/CU. + W2 conv tail work (r11). Grid: (DMLP/BN, NTILES).
// ---------------------------------------------------------------------------
__global__ __launch_bounds__(256)
void gemm1_kernel(const unsigned short* __restrict__ xg,
                  const unsigned short* __restrict__ W1T,
                  const float* __restrict__ b1, const int* __restrict__ tile_e,
                  unsigned short* __restrict__ h,
                  const float* __restrict__ W2, unsigned short* __restrict__ W2T) {
  const int bt = blockIdx.y;                 // row tile
  const int te = tile_e[bt];
  const int n0 = blockIdx.x * BN;            // col tile
  const int tid = threadIdx.x;

  // 64 KB: buf b at [b*16384, b*16384+16384): A first 8192 shorts, B next.
  __shared__ __align__(16) unsigned short SMEM[32768];

  if (te >= 0) {
    const unsigned short* Asrc = xg + (size_t)bt * BM * DIM;
    const unsigned short* Bsrc = W1T + (size_t)te * DIM * DMLP + (size_t)n0 * 8;

    // A: granule p = t*256+tid -> r = 32t + (tid>>3), c = tid&7 swizzled
    const int rr = tid >> 3;
    const int cs = (tid & 7) ^ (rr & 7);
    const unsigned short* a0 = Asrc + (size_t)rr * DIM + cs * 8;
    // B: granule p -> C = 2t + (tid>>7), n = tid&127
    const unsigned short* b0 = Bsrc + ((size_t)(tid >> 7) * DMLP + (tid & 127)) * 8;

    const int wid = tid >> 6, lane = tid & 63;
    const int wm = (wid >> 1) * 64, wn = (wid & 1) * 64;
    const int l15 = lane & 15, quad = lane >> 4;

    float4v acc[4][4];
#pragma unroll
    for (int i = 0; i < 4; i++)
#pragma unroll
      for (int j = 0; j < 4; j++) acc[i][j] = (float4v){0.f, 0.f, 0.f, 0.f};

#define STAGE1(buf, k0) do {                                                   \
    const int kg0_ = (k0) >> 3;                                                \
    _Pragma("unroll")                                                          \
    for (int t = 0; t < 4; t++)                                                \
      ASYNC16(a0 + (size_t)(32 * t) * DIM + (k0),                              \
              &SMEM[(buf) * 16384 + (t * 256 + tid) * 8]);                     \
    _Pragma("unroll")                                                          \
    for (int t = 0; t < 4; t++)                                                \
      ASYNC16(b0 + (size_t)(kg0_ + 2 * t) * DMLP * 8,                          \
              &SMEM[(buf) * 16384 + 8192 + (t * 256 + tid) * 8]);              \
  } while (0)

#define COMPUTE1(buf) do {                                                     \
    _Pragma("unroll")                                                          \
    for (int hh = 0; hh < 2; hh++) {                                           \
      short8 a[4], b[4];                                                       \
      const int C = hh * 4 + quad;                                             \
      _Pragma("unroll")                                                        \
      for (int i = 0; i < 4; i++)                                              \
        a[i] = *(const short8*)&SMEM[(buf) * 16384 + FRAG_OFF(wm + i * 16 + l15, C)]; \
      _Pragma("unroll")                                                        \
      for (int j = 0; j < 4; j++)                                              \
        b[j] = *(const short8*)&SMEM[(buf) * 16384 + 8192 + BOFF(C, wn + j * 16 + l15)]; \
      _Pragma("unroll")                                                        \
      for (int i = 0; i < 4; i++)                                              \
        _Pragma("unroll")                                                      \
        for (int j = 0; j < 4; j++)                                            \
          acc[i][j] = __builtin_amdgcn_mfma_f32_16x16x32_bf16(a[i], b[j],      \
                                                              acc[i][j], 0, 0, 0); \
    }                                                                          \
  } while (0)

    STAGE1(0, 0);
    int cur = 0;
    for (int i = 0; i < DIM / BK; i++) {
      if (i < DIM / BK - 1) {
        STAGE1(cur ^ 1, (i + 1) * BK);
        __builtin_amdgcn_sched_barrier(0);
        asm volatile("s_waitcnt vmcnt(8)" ::: "memory");   // previous tile done
      } else {
        asm volatile("s_waitcnt vmcnt(0)" ::: "memory");   // final tile
      }
      __builtin_amdgcn_s_barrier();
      __builtin_amdgcn_sched_barrier(0);
      COMPUTE1(cur);
      __builtin_amdgcn_s_barrier();      // all reads of buf done before reuse
      cur ^= 1;
    }
#undef STAGE1
#undef COMPUTE1

    // ---- epilogue: gelu -> bf16 into LDS tile, then coalesced wide stores --
#pragma unroll
    for (int i = 0; i < 4; i++) {
#pragma unroll
      for (int j = 0; j < 4; j++) {
        const int colL = wn + j * 16 + l15;
        const float bias = b1[te * DMLP + n0 + colL];
#pragma unroll
        for (int r = 0; r < 4; r++) {
          const int rowL = wm + i * 16 + quad * 4 + r;
          SMEM[rowL * BN + colL] = f2bf(gelu_erf(acc[i][j][r] + bias));
        }
      }
    }
    __syncthreads();
    const int gg = tid & 15;
    const int rb = tid >> 4;
#pragma unroll
    for (int p = 0; p < 8; p++) {
      const int rowL = rb + p * 16;
      const ull2 v = *(const ull2*)&SMEM[rowL * BN + gg * 8];
      *(ull2*)&h[(size_t)(bt * BM + rowL) * DMLP + n0 + gg * 8] = v;
    }
  }

  // ---- tail: convert this block's share of W2 -> W2T (4096 chunks) -------
  const int fb = bt * gridDim.x + blockIdx.x;   // flat block id, 0..1279
#pragma unroll
  for (int r = 0; r < 4; r++) {
    const int c = fb + 1280 * r;
    if (c < 4096) {
      convpack_body(W2, W2T, DMLP, DIM, c & 511, 0, c >> 9, tid);
    }
  }
}

// ---------------------------------------------------------------------------
// Kernel 4: out[tok] = h @ W2 + b2, scatter. 256x64 supertile, BK=64,
// same counted-vmcnt double-buffer schedule (10 loads/step).
// LDS 80 KB -> 2 blocks/CU. Grid: (DIM/64, MAXSUP).
// ---------------------------------------------------------------------------
__global__ __launch_bounds__(256)
void gemm2_kernel(const unsigned short* __restrict__ h,
                  const unsigned short* __restrict__ W2T,
                  const float* __restrict__ b2, const int* __restrict__ perm,
                  const int* __restrict__ supA, const int* __restrict__ supB,
                  const int* __restrict__ supE, float* __restrict__ out) {
  const int s  = blockIdx.y;
  const int te = supE[s];
  if (te < 0) return;
  const int rowA = supA[s], rowB = supB[s];
  const int n0 = blockIdx.x * BN2;
  const int tid = threadIdx.x;

  __shared__ __align__(16) unsigned short As[2][16384];  // 2 x 32 KB
  __shared__ __align__(16) unsigned short Bs[2][4096];   // 2 x 8 KB

  const int rr = tid >> 3;
  const int cs = (tid & 7) ^ (rr & 7);
  const unsigned short* aA = h + (size_t)(rowA + rr) * DMLP + cs * 8;
  const unsigned short* aB = h + (size_t)(rowB + rr) * DMLP + cs * 8;
  // B: granule p = t*256+tid -> C = 4t + (tid>>6), n = tid&63
  const unsigned short* b0 = W2T + (size_t)te * DMLP * DIM
                           + ((size_t)(tid >> 6) * DIM + n0 + (tid & 63)) * 8;

  const int wid = tid >> 6, lane = tid & 63;
  const int wm = wid * 64;                   // 64 rows per wave
  const int l15 = lane & 15, quad = lane >> 4;

  float4v acc[4][4];
#pragma unroll
  for (int i = 0; i < 4; i++)
#pragma unroll
    for (int j = 0; j < 4; j++) acc[i][j] = (float4v){0.f, 0.f, 0.f, 0.f};

#define STAGE2(buf, k0) do {                                                   \
    const int kg0_ = (k0) >> 3;                                                \
    _Pragma("unroll")                                                          \
    for (int t = 0; t < 4; t++)                                                \
      ASYNC16(aA + (size_t)(32 * t) * DMLP + (k0),                             \
              &As[buf][(t * 256 + tid) * 8]);                                  \
    _Pragma("unroll")                                                          \
    for (int t = 0; t < 4; t++)                                                \
      ASYNC16(aB + (size_t)(32 * t) * DMLP + (k0),                             \
              &As[buf][((t + 4) * 256 + tid) * 8]);                            \
    _Pragma("unroll")                                                          \
    for (int t = 0; t < 2; t++)                                                \
      ASYNC16(b0 + (size_t)(kg0_ + 4 * t) * DIM * 8,                           \
              &Bs[buf][(t * 256 + tid) * 8]);                                  \
  } while (0)

#define COMPUTE2(buf) do {                                                     \
    _Pragma("unroll")                                                          \
    for (int hh = 0; hh < 2; hh++) {                                           \
      short8 a[4], b[4];                                                       \
      const int C = hh * 4 + quad;                                             \
      _Pragma("unroll")                                                        \
      for (int i = 0; i < 4; i++)                                              \
        a[i] = *(const short8*)&As[buf][FRAG_OFF(wm + i * 16 + l15, C)];       \
      _Pragma("unroll")                                                        \
      for (int j = 0; j < 4; j++)                                              \
        b[j] = *(const short8*)&Bs[buf][((C << 6) + j * 16 + l15) << 3];       \
      _Pragma("unroll")                                                        \
      for (int i = 0; i < 4; i++)                                              \
        _Pragma("unroll")                                                      \
        for (int j = 0; j < 4; j++)                                            \
          acc[i][j] = __builtin_amdgcn_mfma_f32_16x16x32_bf16(a[i], b[j],      \
                                                              acc[i][j], 0, 0, 0); \
    }                                                                          \
  } while (0)

  STAGE2(0, 0);
  int cur = 0;
  for (int i = 0; i < DMLP / BK; i++) {
    if (i < DMLP / BK - 1) {
      STAGE2(cur ^ 1, (i + 1) * BK);
      __builtin_amdgcn_sched_barrier(0);
      asm volatile("s_waitcnt vmcnt(10)" ::: "memory");   // previous tile done
    } else {
      asm volatile("s_waitcnt vmcnt(0)" ::: "memory");
    }
    __builtin_amdgcn_s_barrier();
    __builtin_amdgcn_sched_barrier(0);
    COMPUTE2(cur);
    __builtin_amdgcn_s_barrier();
    cur ^= 1;
  }
#undef STAGE2
#undef COMPUTE2

  const int halfbase = (wm < 128) ? (rowA + wm) : (rowB + (wm - 128));
#pragma unroll
  for (int i = 0; i < 4; i++) {
#pragma unroll
    for (int j = 0; j < 4; j++) {
      const int col = n0 + j * 16 + l15;
      const float bias = b2[te * DIM + col];
#pragma unroll
      for (int r = 0; r < 4; r++) {
        const int slot = halfbase + i * 16 + quad * 4 + r;
        const int t    = perm[slot];
        if (t >= 0) out[(size_t)t * DIM + col] = acc[i][j][r] + bias;
      }
    }
  }
}

// ---------------------------------------------------------------------------
extern "C" void kernel_launch(void* const* d_in, const int* in_sizes, int n_in,
                              void* d_out, int out_size, void* d_ws, size_t ws_size,
                              hipStream_t stream) {
  const float* x    = (const float*)d_in[0];
  const int*   eidx = (const int*)d_in[1];
  const float* W1   = (const float*)d_in[2];
  const float* b1   = (const float*)d_in[3];
  const float* W2   = (const float*)d_in[4];
  const float* b2   = (const float*)d_in[5];
  float* out = (float*)d_out;

  char* ws = (char*)d_ws;
  int* perm   = (int*)ws;                              // 5120 ints
  int* tile_e = (int*)(ws + PADMAX * sizeof(int));     // 40 ints
  int* supA   = (int*)(ws + 20736);                    // 24 ints
  int* supB   = (int*)(ws + 20832);                    // 24 ints
  int* supE   = (int*)(ws + 20928);                    // 24 ints
  unsigned short* xg  = (unsigned short*)(ws + 32768);                      // 10 MB
  unsigned short* h   = (unsigned short*)(ws + 32768 + 10485760);           // 40 MB
  unsigned short* W1T = (unsigned short*)(ws + 32768 + 10485760 + 41943040);// 64 MB
  unsigned short* W2T = (unsigned short*)((char*)W1T + 67108864);           // 64 MB

  group_kernel<<<1, 256, 0, stream>>>(eidx, perm, tile_e, supA, supB, supE);
  prep1_kernel<<<4096 + PADMAX, 256, 0, stream>>>(W1, W1T, x, perm, xg);
  gemm1_kernel<<<dim3(DMLP / BN, NTILES), 256, 0, stream>>>(xg, W1T, b1, tile_e, h, W2, W2T);
  gemm2_kernel<<<dim3(DIM / BN2, MAXSUP), 256, 0, stream>>>(h, W2T, b2, perm, supA, supB, supE, out);
}